// Round 1
// baseline (1376.911 us; speedup 1.0000x reference)
//
#include <hip/hip_runtime.h>
#include <math.h>

#define BB 8
#define NN 1024
#define HH 256
#define ALPHAC 0.25f

// ---------------- workspace layout (float offsets) ----------------
// tmp   : [8192][512]   (tmp[b,i,k*256+g])           4,194,304 f
// M     : [8][1024][1024] Laplacian / LU in place    8,388,608 f  (r1pre aliases first 2M)
// small : head0/head1/dep0/dep1/rs [8192] each, gold[8], slog[8], neg[8](int), zer[8](int)
static const size_t OFF_TMP = 0;
static const size_t SZ_TMP  = (size_t)8192 * 512;
static const size_t OFF_M   = OFF_TMP + SZ_TMP;
static const size_t SZ_M    = (size_t)8 * 1024 * 1024;
static const size_t OFF_SM  = OFF_M + SZ_M;
static const size_t O_H0 = 0, O_H1 = 8192, O_D0 = 16384, O_D1 = 24576, O_RS = 32768;
static const size_t O_GOLD = 40960, O_SLOG = 40968, O_NEG = 40976, O_ZER = 40984;

// ---------------- K1: tmp (bilinear pre-products) + r1pre ----------------
// C[row][col], row in [0,8192), col in [0,768):
//   col<512: tmp[row][col] = sum_h h[row][h] * W_bilin[col>>8][h][col&255]
//   col>=512: r1pre[row][col-512] = sum_h h[row][h] * W_r1[col-512][h]
__global__ __launch_bounds__(256) void k1_rowfeat(const float* __restrict__ h_cat,
    const float* __restrict__ W_bilin, const float* __restrict__ W_r1,
    float* __restrict__ tmp, float* __restrict__ r1pre) {
  __shared__ __align__(16) float As[64][36];
  __shared__ __align__(16) float Bs[64][36];
  int tid = threadIdx.x;
  int tx = tid & 15, ty = tid >> 4;
  int m0 = blockIdx.y * 64;
  int nt = blockIdx.x;
  int n0 = nt * 64;
  float acc[4][4] = {};
  for (int ch = 0; ch < 8; ++ch) {
    int k0 = ch * 32;
#pragma unroll
    for (int i = 0; i < 8; ++i) {
      int idx = tid + i * 256;
      int r = idx >> 5, c = idx & 31;
      As[r][c] = h_cat[(m0 + r) * 256 + k0 + c];
    }
    if (nt < 8) {
      int kb = n0 >> 8;
      int g0 = n0 & 255;
#pragma unroll
      for (int i = 0; i < 8; ++i) {
        int idx = tid + i * 256;
        int kR = idx >> 6, n = idx & 63;
        Bs[n][kR] = W_bilin[kb * 65536 + (k0 + kR) * 256 + g0 + n];
      }
    } else {
      int c0 = n0 - 512;
#pragma unroll
      for (int i = 0; i < 8; ++i) {
        int idx = tid + i * 256;
        int n = idx >> 5, kR = idx & 31;
        Bs[n][kR] = W_r1[(c0 + n) * 256 + k0 + kR];
      }
    }
    __syncthreads();
#pragma unroll
    for (int kk = 0; kk < 32; kk += 4) {
      float4 a4[4], b4[4];
#pragma unroll
      for (int r = 0; r < 4; ++r) a4[r] = *(const float4*)&As[ty * 4 + r][kk];
#pragma unroll
      for (int c = 0; c < 4; ++c) b4[c] = *(const float4*)&Bs[tx * 4 + c][kk];
#pragma unroll
      for (int r = 0; r < 4; ++r)
#pragma unroll
        for (int c = 0; c < 4; ++c)
          acc[r][c] += a4[r].x * b4[c].x + a4[r].y * b4[c].y + a4[r].z * b4[c].z + a4[r].w * b4[c].w;
    }
    __syncthreads();
  }
  if (nt < 8) {
#pragma unroll
    for (int r = 0; r < 4; ++r) {
      int row = m0 + ty * 4 + r;
      float4 v = make_float4(acc[r][0], acc[r][1], acc[r][2], acc[r][3]);
      *(float4*)&tmp[(size_t)row * 512 + n0 + tx * 4] = v;
    }
  } else {
#pragma unroll
    for (int r = 0; r < 4; ++r) {
      int row = m0 + ty * 4 + r;
      float4 v = make_float4(acc[r][0], acc[r][1], acc[r][2], acc[r][3]);
      *(float4*)&r1pre[(size_t)row * 256 + (n0 - 512) + tx * 4] = v;
    }
  }
}

// ---------------- K1b: head/dep scalars + root scores (GELU) ----------------
__global__ __launch_bounds__(256) void k1b_rowscal(const float* __restrict__ h_cat,
    const float* __restrict__ W_head, const float* __restrict__ W_dep,
    const float* __restrict__ b_r1, const float* __restrict__ W_r2,
    const float* __restrict__ b_r2, const float* __restrict__ r1pre,
    float* __restrict__ head0, float* __restrict__ head1,
    float* __restrict__ dep0, float* __restrict__ dep1, float* __restrict__ rs) {
  int wave = threadIdx.x >> 6;
  int lane = threadIdx.x & 63;
  int row = blockIdx.x * 4 + wave;
  float4 h4  = *(const float4*)&h_cat[(size_t)row * 256 + lane * 4];
  float4 wh0 = *(const float4*)&W_head[lane * 4];
  float4 wh1 = *(const float4*)&W_head[256 + lane * 4];
  float4 wd0 = *(const float4*)&W_dep[lane * 4];
  float4 wd1 = *(const float4*)&W_dep[256 + lane * 4];
  float4 r14 = *(const float4*)&r1pre[(size_t)row * 256 + lane * 4];
  float4 br4 = *(const float4*)&b_r1[lane * 4];
  float4 wr2 = *(const float4*)&W_r2[lane * 4];
  float s0 = h4.x * wh0.x + h4.y * wh0.y + h4.z * wh0.z + h4.w * wh0.w;
  float s1 = h4.x * wh1.x + h4.y * wh1.y + h4.z * wh1.z + h4.w * wh1.w;
  float s2 = h4.x * wd0.x + h4.y * wd0.y + h4.z * wd0.z + h4.w * wd0.w;
  float s3 = h4.x * wd1.x + h4.y * wd1.y + h4.z * wd1.z + h4.w * wd1.w;
  float xa = r14.x + br4.x, xb = r14.y + br4.y, xc = r14.z + br4.z, xd = r14.w + br4.w;
  float ga = 0.5f * xa * (1.0f + erff(xa * 0.70710678118654752f));
  float gb = 0.5f * xb * (1.0f + erff(xb * 0.70710678118654752f));
  float gc = 0.5f * xc * (1.0f + erff(xc * 0.70710678118654752f));
  float gd = 0.5f * xd * (1.0f + erff(xd * 0.70710678118654752f));
  float s4 = ga * wr2.x + gb * wr2.y + gc * wr2.z + gd * wr2.w;
#pragma unroll
  for (int off = 32; off; off >>= 1) {
    s0 += __shfl_down(s0, off);
    s1 += __shfl_down(s1, off);
    s2 += __shfl_down(s2, off);
    s3 += __shfl_down(s3, off);
    s4 += __shfl_down(s4, off);
  }
  if (lane == 0) {
    head0[row] = s0; head1[row] = s1; dep0[row] = s2; dep1[row] = s3;
    rs[row] = s4 + b_r2[0];
  }
}

// ---------------- K2: compat -> -A into M, plus gold edge sum ----------------
__global__ __launch_bounds__(256) void k2_compat(const float* __restrict__ h_cat,
    const float* __restrict__ tmp, const float* __restrict__ left,
    const float* __restrict__ right, const float* __restrict__ b_bilin,
    const float* __restrict__ head0, const float* __restrict__ head1,
    const float* __restrict__ dep0, const float* __restrict__ dep1,
    float* __restrict__ M, float* __restrict__ gold) {
  __shared__ __align__(16) float A0s[64][36];
  __shared__ __align__(16) float A1s[64][36];
  __shared__ __align__(16) float Bs[64][36];
  __shared__ float red[256];
  int tid = threadIdx.x;
  int tx = tid & 15, ty = tid >> 4;
  int b = blockIdx.z;
  int i0 = blockIdx.y * 64, j0 = blockIdx.x * 64;
  const float* hb = h_cat + (size_t)b * NN * HH;
  const float* tb = tmp + (size_t)b * NN * 512;
  float acc0[4][4] = {}, acc1[4][4] = {};
  for (int ch = 0; ch < 8; ++ch) {
    int g0 = ch * 32;
#pragma unroll
    for (int i = 0; i < 8; ++i) {
      int idx = tid + i * 256;
      int r = idx >> 5, c = idx & 31;
      A0s[r][c] = tb[(size_t)(i0 + r) * 512 + g0 + c];
      A1s[r][c] = tb[(size_t)(i0 + r) * 512 + 256 + g0 + c];
      Bs[r][c]  = hb[(size_t)(j0 + r) * 256 + g0 + c];
    }
    __syncthreads();
#pragma unroll
    for (int kk = 0; kk < 32; kk += 4) {
      float4 a0[4], a1[4], b4[4];
#pragma unroll
      for (int r = 0; r < 4; ++r) { a0[r] = *(const float4*)&A0s[ty * 4 + r][kk];
                                    a1[r] = *(const float4*)&A1s[ty * 4 + r][kk]; }
#pragma unroll
      for (int c = 0; c < 4; ++c) b4[c] = *(const float4*)&Bs[tx * 4 + c][kk];
#pragma unroll
      for (int r = 0; r < 4; ++r)
#pragma unroll
        for (int c = 0; c < 4; ++c) {
          acc0[r][c] += a0[r].x * b4[c].x + a0[r].y * b4[c].y + a0[r].z * b4[c].z + a0[r].w * b4[c].w;
          acc1[r][c] += a1[r].x * b4[c].x + a1[r].y * b4[c].y + a1[r].z * b4[c].z + a1[r].w * b4[c].w;
        }
    }
    __syncthreads();
  }
  float bb0 = b_bilin[0], bb1 = b_bilin[1];
  float4 dp0v = *(const float4*)&dep0[b * NN + j0 + tx * 4];
  float4 dp1v = *(const float4*)&dep1[b * NN + j0 + tx * 4];
  float dp0a[4] = {dp0v.x, dp0v.y, dp0v.z, dp0v.w};
  float dp1a[4] = {dp1v.x, dp1v.y, dp1v.z, dp1v.w};
  float4 h0v = *(const float4*)&head0[b * NN + i0 + ty * 4];
  float4 h1v = *(const float4*)&head1[b * NN + i0 + ty * 4];
  float h0a[4] = {h0v.x, h0v.y, h0v.z, h0v.w};
  float h1a[4] = {h1v.x, h1v.y, h1v.z, h1v.w};
  size_t Mb = (size_t)b * NN * NN;
  float gsum = 0.f;
#pragma unroll
  for (int r = 0; r < 4; ++r) {
    int i = i0 + ty * 4 + r;
    size_t off = Mb + (size_t)i * NN + j0 + tx * 4;
    float4 l4 = *(const float4*)&left[off];
    float4 r4 = *(const float4*)&right[off];
    float la[4] = {l4.x, l4.y, l4.z, l4.w};
    float ra[4] = {r4.x, r4.y, r4.z, r4.w};
    float outv[4];
#pragma unroll
    for (int c = 0; c < 4; ++c) {
      float c0 = acc0[r][c] + h0a[r] + dp0a[c] + bb0;
      float c1 = acc1[r][c] + h1a[r] + dp1a[c] + bb1;
      gsum += c0 * la[c] + c1 * ra[c];
      outv[c] = -(expf(c0) + expf(c1));
    }
    *(float4*)&M[off] = make_float4(outv[0], outv[1], outv[2], outv[3]);
  }
  red[tid] = gsum;
  __syncthreads();
#pragma unroll
  for (int s = 128; s; s >>= 1) { if (tid < s) red[tid] += red[tid + s]; __syncthreads(); }
  if (tid == 0) atomicAdd(&gold[b], red[0]);
}

// ---------------- K3: column sums -> diag, row0 = exp(root_scores) ----------------
__global__ __launch_bounds__(256) void k3_colsum(float* __restrict__ M, const float* __restrict__ rs) {
  int j = blockIdx.x * 256 + threadIdx.x;
  int b = blockIdx.y;
  float* Mb = M + (size_t)b * NN * NN;
  float s = 0.f;
#pragma unroll 8
  for (int i = 0; i < NN; ++i) s += Mb[(size_t)i * NN + j];
  Mb[(size_t)j * NN + j] -= s;          // += colsum  (M holds -A, s = -colsum)
  Mb[j] = expf(rs[b * NN + j]);         // row 0 replacement
}

// ---------------- K4a: exact LU factor of the first 64x64 block ----------------
__global__ __launch_bounds__(256) void k4a_diag0(float* __restrict__ M,
    float* __restrict__ slog, int* __restrict__ negc, int* __restrict__ zerc) {
  __shared__ float T[64][65];
  __shared__ float red[256];
  __shared__ int redi[256];
  int b = blockIdx.x, tid = threadIdx.x;
  float* Mb = M + (size_t)b * NN * NN;
  for (int idx = tid; idx < 4096; idx += 256) T[idx >> 6][idx & 63] = Mb[(size_t)(idx >> 6) * NN + (idx & 63)];
  __syncthreads();
  for (int j = 0; j < 63; ++j) {
    float inv = 1.0f / T[j][j];
    int nr = 63 - j;
    for (int idx = tid; idx < nr * nr; idx += 256) {
      int r = j + 1 + idx / nr;
      int c = j + 1 + idx % nr;
      T[r][c] -= T[r][j] * inv * T[j][c];
    }
    __syncthreads();
    if (tid < nr) T[j + 1 + tid][j] *= inv;
    __syncthreads();
  }
  float lf = 0.f; int flg = 0;
  if (tid < 64) {
    float d = T[tid][tid];
    lf = logf(fabsf(d));
    flg = (d < 0.f ? 1 : 0) + (d == 0.f ? (1 << 16) : 0);
  }
  red[tid] = lf; redi[tid] = flg;
  __syncthreads();
#pragma unroll
  for (int s = 128; s; s >>= 1) { if (tid < s) { red[tid] += red[tid + s]; redi[tid] += redi[tid + s]; } __syncthreads(); }
  if (tid == 0) { atomicAdd(&slog[b], red[0]); atomicAdd(&negc[b], redi[0] & 0xffff); atomicAdd(&zerc[b], redi[0] >> 16); }
  __syncthreads();
  for (int idx = tid; idx < 4096; idx += 256) Mb[(size_t)(idx >> 6) * NN + (idx & 63)] = T[idx >> 6][idx & 63];
}

// ---------------- K4b: exact triangular solves for step 0 panels ----------------
__global__ __launch_bounds__(64) void k4b_tsolve0(float* __restrict__ M) {
  __shared__ float U[64][65];
  __shared__ float Tt[64][65];
  __shared__ float invd[64];
  int lane = threadIdx.x;
  int t = blockIdx.x, b = blockIdx.y, mode = blockIdx.z;
  float* Mb = M + (size_t)b * NN * NN;
  for (int rr = 0; rr < 64; ++rr) U[rr][lane] = Mb[(size_t)rr * NN + lane];
  __syncthreads();
  invd[lane] = 1.0f / U[lane][lane];
  if (mode == 0) {
    int i0 = 64 + t * 64;
    for (int rr = 0; rr < 64; ++rr) Tt[rr][lane] = Mb[(size_t)(i0 + rr) * NN + lane];
    __syncthreads();
    float x[64];
#pragma unroll
    for (int j = 0; j < 64; ++j) {
      float a = Tt[lane][j];
#pragma unroll
      for (int tt = 0; tt < j; ++tt) a -= x[tt] * U[tt][j];
      x[j] = a * invd[j];
    }
#pragma unroll
    for (int j = 0; j < 64; ++j) Tt[lane][j] = x[j];
    __syncthreads();
    for (int rr = 0; rr < 64; ++rr) Mb[(size_t)(i0 + rr) * NN + lane] = Tt[rr][lane];
  } else {
    int c0 = 64 + t * 64;
    for (int rr = 0; rr < 64; ++rr) Tt[rr][lane] = Mb[(size_t)rr * NN + c0 + lane];
    __syncthreads();
    float y[64];
#pragma unroll
    for (int j = 0; j < 64; ++j) {
      float a = Tt[j][lane];
#pragma unroll
      for (int tt = 0; tt < j; ++tt) a -= U[j][tt] * y[tt];
      y[j] = a;
    }
#pragma unroll
    for (int j = 0; j < 64; ++j) Tt[j][lane] = y[j];
    __syncthreads();
    for (int rr = 0; rr < 64; ++rr) Mb[(size_t)rr * NN + c0 + lane] = Tt[rr][lane];
  }
}

// ---------------- K5: approximate panel prep for steps >= 1 ----------------
// L21 := A21 * (Dd^-1 - Dd^-1*SU*Dd^-1) ; U12 := (I - SL*Dd^-1) * A12 ; pivots = diag(D)
__global__ __launch_bounds__(256) void k5_prep(float* __restrict__ M, int k0, int T,
    float* __restrict__ slog, int* __restrict__ negc, int* __restrict__ zerc) {
  __shared__ float D[64][65];
  __shared__ float Wm[64][65];
  __shared__ float At[64][65];
  __shared__ float invd[64];
  __shared__ float red[256];
  __shared__ int redi[256];
  int tid = threadIdx.x;
  int task = blockIdx.x, b = blockIdx.y;
  float* Mb = M + (size_t)b * NN * NN;
  for (int idx = tid; idx < 4096; idx += 256)
    D[idx >> 6][idx & 63] = Mb[(size_t)(k0 + (idx >> 6)) * NN + k0 + (idx & 63)];
  __syncthreads();
  if (task == 2 * T) {
    float lf = 0.f; int flg = 0;
    if (tid < 64) {
      float d = D[tid][tid];
      lf = logf(fabsf(d));
      flg = (d < 0.f ? 1 : 0) + (d == 0.f ? (1 << 16) : 0);
    }
    red[tid] = lf; redi[tid] = flg;
    __syncthreads();
#pragma unroll
    for (int s = 128; s; s >>= 1) { if (tid < s) { red[tid] += red[tid + s]; redi[tid] += redi[tid + s]; } __syncthreads(); }
    if (tid == 0) { atomicAdd(&slog[b], red[0]); atomicAdd(&negc[b], redi[0] & 0xffff); atomicAdd(&zerc[b], redi[0] >> 16); }
    return;
  }
  if (tid < 64) invd[tid] = 1.0f / D[tid][tid];
  __syncthreads();
  int tx = tid & 15, ty = tid >> 4;
  float acc[4][4] = {};
  if (task < T) {
    int i0 = k0 + 64 + task * 64;
    for (int idx = tid; idx < 4096; idx += 256) {
      int r = idx >> 6, c = idx & 63;
      Wm[r][c] = (r == c) ? invd[r] : ((r < c) ? -D[r][c] * invd[r] * invd[c] : 0.f);
      At[r][c] = Mb[(size_t)(i0 + r) * NN + k0 + c];
    }
    __syncthreads();
    for (int k = 0; k < 64; ++k) {
      float a[4], w[4];
#pragma unroll
      for (int r = 0; r < 4; ++r) a[r] = At[ty * 4 + r][k];
#pragma unroll
      for (int c = 0; c < 4; ++c) w[c] = Wm[k][tx * 4 + c];
#pragma unroll
      for (int r = 0; r < 4; ++r)
#pragma unroll
        for (int c = 0; c < 4; ++c) acc[r][c] += a[r] * w[c];
    }
#pragma unroll
    for (int r = 0; r < 4; ++r)
      *(float4*)&Mb[(size_t)(i0 + ty * 4 + r) * NN + k0 + tx * 4] =
          make_float4(acc[r][0], acc[r][1], acc[r][2], acc[r][3]);
  } else {
    int c0 = k0 + 64 + (task - T) * 64;
    for (int idx = tid; idx < 4096; idx += 256) {
      int r = idx >> 6, c = idx & 63;
      Wm[r][c] = (r == c) ? 1.f : ((r > c) ? -D[r][c] * invd[c] : 0.f);
      At[r][c] = Mb[(size_t)(k0 + r) * NN + c0 + c];
    }
    __syncthreads();
    for (int k = 0; k < 64; ++k) {
      float w[4], a[4];
#pragma unroll
      for (int r = 0; r < 4; ++r) w[r] = Wm[ty * 4 + r][k];
#pragma unroll
      for (int c = 0; c < 4; ++c) a[c] = At[k][tx * 4 + c];
#pragma unroll
      for (int r = 0; r < 4; ++r)
#pragma unroll
        for (int c = 0; c < 4; ++c) acc[r][c] += w[r] * a[c];
    }
#pragma unroll
    for (int r = 0; r < 4; ++r)
      *(float4*)&Mb[(size_t)(k0 + ty * 4 + r) * NN + c0 + tx * 4] =
          make_float4(acc[r][0], acc[r][1], acc[r][2], acc[r][3]);
  }
}

// ---------------- K6: trailing update A22 -= L21 * U12 ----------------
__global__ __launch_bounds__(256) void k6_gemm(float* __restrict__ M, int k0) {
  __shared__ __align__(16) float Al[64][68];
  __shared__ __align__(16) float Bl[64][68];
  int tid = threadIdx.x, tx = tid & 15, ty = tid >> 4;
  int b = blockIdx.z;
  int i0 = k0 + 64 + blockIdx.y * 64;
  int j0 = k0 + 64 + blockIdx.x * 64;
  float* Mb = M + (size_t)b * NN * NN;
  for (int idx = tid; idx < 4096; idx += 256) {
    int r = idx >> 6, c = idx & 63;
    Al[r][c] = Mb[(size_t)(i0 + r) * NN + k0 + c];
    Bl[r][c] = Mb[(size_t)(k0 + r) * NN + j0 + c];
  }
  __syncthreads();
  float acc[4][4] = {};
#pragma unroll
  for (int kk = 0; kk < 64; kk += 4) {
    float4 a4[4], b4[4];
#pragma unroll
    for (int r = 0; r < 4; ++r) a4[r] = *(const float4*)&Al[ty * 4 + r][kk];
#pragma unroll
    for (int q = 0; q < 4; ++q) b4[q] = *(const float4*)&Bl[kk + q][tx * 4];
#pragma unroll
    for (int r = 0; r < 4; ++r) {
      float4 a = a4[r];
      acc[r][0] += a.x * b4[0].x + a.y * b4[1].x + a.z * b4[2].x + a.w * b4[3].x;
      acc[r][1] += a.x * b4[0].y + a.y * b4[1].y + a.z * b4[2].y + a.w * b4[3].y;
      acc[r][2] += a.x * b4[0].z + a.y * b4[1].z + a.z * b4[2].z + a.w * b4[3].z;
      acc[r][3] += a.x * b4[0].w + a.y * b4[1].w + a.z * b4[2].w + a.w * b4[3].w;
    }
  }
#pragma unroll
  for (int r = 0; r < 4; ++r) {
    size_t off = (size_t)(i0 + ty * 4 + r) * NN + j0 + tx * 4;
    float4 cv = *(float4*)&Mb[off];
    cv.x -= acc[r][0]; cv.y -= acc[r][1]; cv.z -= acc[r][2]; cv.w -= acc[r][3];
    *(float4*)&Mb[off] = cv;
  }
}

// ---------------- K7: final loss ----------------
__global__ void k7_final(const float* __restrict__ rs, const int* __restrict__ roots,
    const float* __restrict__ gold_e, const float* __restrict__ slog,
    const int* __restrict__ negc, const int* __restrict__ zerc, float* __restrict__ out) {
  if (threadIdx.x == 0 && blockIdx.x == 0) {
    float s = 0.f;
    for (int b = 0; b < BB; ++b) {
      int root = roots[b];
      float gold = rs[b * NN + root] + gold_e[b];
      float ld = slog[b];
      bool pos = ((negc[b] & 1) == 0) && (zerc[b] == 0);
      float loss = 0.f;
      if (pos && !isnan(ld) && !isnan(gold)) {
        if (gold <= ld) loss = ld - gold;
      }
      if (isnan(loss) || isinf(loss)) loss = 0.f;
      s += loss;
    }
    out[0] = ALPHAC * s / (float)BB;
  }
}

extern "C" void kernel_launch(void* const* d_in, const int* in_sizes, int n_in,
                              void* d_out, int out_size, void* d_ws, size_t ws_size,
                              hipStream_t stream) {
  (void)in_sizes; (void)n_in; (void)out_size; (void)ws_size;
  const float* h_cat  = (const float*)d_in[0];
  const float* left   = (const float*)d_in[1];
  const float* right  = (const float*)d_in[2];
  const int*   roots  = (const int*)d_in[3];
  const float* W_bilin = (const float*)d_in[4];
  const float* b_bilin = (const float*)d_in[5];
  const float* W_head = (const float*)d_in[6];
  const float* W_dep  = (const float*)d_in[7];
  const float* W_r1   = (const float*)d_in[8];
  const float* b_r1   = (const float*)d_in[9];
  const float* W_r2   = (const float*)d_in[10];
  const float* b_r2   = (const float*)d_in[11];

  float* ws = (float*)d_ws;
  float* tmp   = ws + OFF_TMP;
  float* M     = ws + OFF_M;
  float* r1pre = M;  // alias: consumed by k1b before k2 overwrites M
  float* sm    = ws + OFF_SM;
  float* head0 = sm + O_H0;
  float* head1 = sm + O_H1;
  float* dep0  = sm + O_D0;
  float* dep1  = sm + O_D1;
  float* rs    = sm + O_RS;
  float* gold  = sm + O_GOLD;
  float* slog  = sm + O_SLOG;
  int*   negc  = (int*)(sm + O_NEG);
  int*   zerc  = (int*)(sm + O_ZER);

  hipMemsetAsync(gold, 0, 32 * sizeof(float), stream);  // gold, slog, negc, zerc

  k1_rowfeat<<<dim3(12, 128), 256, 0, stream>>>(h_cat, W_bilin, W_r1, tmp, r1pre);
  k1b_rowscal<<<2048, 256, 0, stream>>>(h_cat, W_head, W_dep, b_r1, W_r2, b_r2, r1pre,
                                        head0, head1, dep0, dep1, rs);
  k2_compat<<<dim3(16, 16, 8), 256, 0, stream>>>(h_cat, tmp, left, right, b_bilin,
                                                 head0, head1, dep0, dep1, M, gold);
  k3_colsum<<<dim3(4, 8), 256, 0, stream>>>(M, rs);
  k4a_diag0<<<8, 256, 0, stream>>>(M, slog, negc, zerc);
  k4b_tsolve0<<<dim3(15, 8, 2), 64, 0, stream>>>(M);
  k6_gemm<<<dim3(15, 15, 8), 256, 0, stream>>>(M, 0);
  for (int s = 1; s <= 15; ++s) {
    int k0 = s * 64, T = 15 - s;
    k5_prep<<<dim3(2 * T + 1, 8), 256, 0, stream>>>(M, k0, T, slog, negc, zerc);
    if (T > 0) k6_gemm<<<dim3(T, T, 8), 256, 0, stream>>>(M, k0);
  }
  k7_final<<<1, 64, 0, stream>>>(rs, roots, gold, slog, negc, zerc, (float*)d_out);
}

// Round 2
// 945.296 us; speedup vs baseline: 1.4566x; 1.4566x over previous
//
#include <hip/hip_runtime.h>
#include <math.h>

#define BB 8
#define NN 1024
#define HH 256
#define ALPHAC 0.25f

typedef short bf16x8 __attribute__((ext_vector_type(8)));
typedef float f32x4 __attribute__((ext_vector_type(4)));

__device__ inline unsigned short f2bf(float x) {
  unsigned u = __builtin_bit_cast(unsigned, x);
  unsigned r = (u + 0x7fffu + ((u >> 16) & 1u)) >> 16;
  return (unsigned short)r;
}

// ---------------- workspace layout (float offsets) ----------------
// [0, 2097152)        tmp_bf  [8192][512] bf16
// [2097152, 3145728)  h_bf    [8192][256] bf16
// [3145728, 3244032)  BT      [768][256]  bf16  (rows 0..511 = W_bilin^T, 512..767 = W_r1)
// [OFF_M, +8388608)   M       [8][1024][1024] f32 (r1pre aliases first 2M floats)
// [OFF_SM ...)        small buffers
static const size_t OFF_TMPBF = 0;
static const size_t OFF_HBF   = 2097152;
static const size_t OFF_BT    = 3145728;
static const size_t OFF_M     = 4194304;
static const size_t SZ_M      = (size_t)8 * 1024 * 1024;
static const size_t OFF_SM    = OFF_M + SZ_M;
static const size_t O_H0 = 0, O_H1 = 8192, O_D0 = 16384, O_D1 = 24576, O_RS = 32768;
static const size_t O_GOLD = 40960, O_SLOG = 40968, O_NEG = 40976, O_ZER = 40984;

// ---------------- K0: cast h -> bf16, build BT (weights, bf16, B^T layout) ----------------
__global__ __launch_bounds__(256) void k0_cast(const float* __restrict__ h_cat,
    const float* __restrict__ Wb, const float* __restrict__ Wr1,
    unsigned short* __restrict__ h_bf, unsigned short* __restrict__ BT) {
  int bid = blockIdx.x, tid = threadIdx.x;
  if (bid < 2048) {
    int idx4 = bid * 256 + tid;            // [0, 524288)
    float4 v = *(const float4*)&h_cat[(size_t)idx4 * 4];
    ushort4 o;
    o.x = f2bf(v.x); o.y = f2bf(v.y); o.z = f2bf(v.z); o.w = f2bf(v.w);
    *(ushort4*)&h_bf[(size_t)idx4 * 4] = o;
  } else if (bid < 2560) {
    int idx = (bid - 2048) * 256 + tid;    // [0, 131072): c=idx>>8 col of output, h=idx&255
    int c = idx >> 8, h = idx & 255;
    BT[(size_t)c * 256 + h] = f2bf(Wb[(size_t)(c >> 8) * 65536 + (size_t)h * 256 + (c & 255)]);
  } else {
    int idx = (bid - 2560) * 256 + tid;    // [0, 65536)
    int c = idx >> 8, h = idx & 255;
    BT[(size_t)(512 + c) * 256 + h] = f2bf(Wr1[(size_t)c * 256 + h]);
  }
}

// ---------------- K1: MFMA GEMM  C[8192][768] = h_bf * BT^T ----------------
// cols<512 -> tmp_bf (bf16), cols>=512 -> r1pre (f32)
__global__ __launch_bounds__(256) void k1_mfma(const unsigned short* __restrict__ h_bf,
    const unsigned short* __restrict__ BT, unsigned short* __restrict__ tmp_bf,
    float* __restrict__ r1pre) {
  int lane = threadIdx.x & 63, w = threadIdx.x >> 6;
  int m0 = blockIdx.y * 64 + w * 16;
  int n0 = blockIdx.x * 64;
  int arow = m0 + (lane & 15);
  int kof = (lane >> 4) * 8;
  f32x4 acc[4] = {};
  const unsigned short* ap = h_bf + (size_t)arow * 256 + kof;
  const unsigned short* bp = BT + (size_t)(n0 + (lane & 15)) * 256 + kof;
#pragma unroll
  for (int kk = 0; kk < 8; ++kk) {
    bf16x8 a = *(const bf16x8*)(ap + kk * 32);
#pragma unroll
    for (int t = 0; t < 4; ++t) {
      bf16x8 b = *(const bf16x8*)(bp + (size_t)t * 16 * 256 + kk * 32);
      acc[t] = __builtin_amdgcn_mfma_f32_16x16x32_bf16(a, b, acc[t], 0, 0, 0);
    }
  }
  int r0 = m0 + (lane >> 4) * 4;
  int cb = lane & 15;
  if (n0 < 512) {
#pragma unroll
    for (int t = 0; t < 4; ++t)
#pragma unroll
      for (int q = 0; q < 4; ++q)
        tmp_bf[(size_t)(r0 + q) * 512 + n0 + 16 * t + cb] = f2bf(acc[t][q]);
  } else {
#pragma unroll
    for (int t = 0; t < 4; ++t)
#pragma unroll
      for (int q = 0; q < 4; ++q)
        r1pre[(size_t)(r0 + q) * 256 + (n0 - 512) + 16 * t + cb] = acc[t][q];
  }
}

// ---------------- K1b: head/dep scalars + root scores (GELU) ----------------
__global__ __launch_bounds__(256) void k1b_rowscal(const float* __restrict__ h_cat,
    const float* __restrict__ W_head, const float* __restrict__ W_dep,
    const float* __restrict__ b_r1, const float* __restrict__ W_r2,
    const float* __restrict__ b_r2, const float* __restrict__ r1pre,
    float* __restrict__ head0, float* __restrict__ head1,
    float* __restrict__ dep0, float* __restrict__ dep1, float* __restrict__ rs) {
  int wave = threadIdx.x >> 6;
  int lane = threadIdx.x & 63;
  int row = blockIdx.x * 4 + wave;
  float4 h4  = *(const float4*)&h_cat[(size_t)row * 256 + lane * 4];
  float4 wh0 = *(const float4*)&W_head[lane * 4];
  float4 wh1 = *(const float4*)&W_head[256 + lane * 4];
  float4 wd0 = *(const float4*)&W_dep[lane * 4];
  float4 wd1 = *(const float4*)&W_dep[256 + lane * 4];
  float4 r14 = *(const float4*)&r1pre[(size_t)row * 256 + lane * 4];
  float4 br4 = *(const float4*)&b_r1[lane * 4];
  float4 wr2 = *(const float4*)&W_r2[lane * 4];
  float s0 = h4.x * wh0.x + h4.y * wh0.y + h4.z * wh0.z + h4.w * wh0.w;
  float s1 = h4.x * wh1.x + h4.y * wh1.y + h4.z * wh1.z + h4.w * wh1.w;
  float s2 = h4.x * wd0.x + h4.y * wd0.y + h4.z * wd0.z + h4.w * wd0.w;
  float s3 = h4.x * wd1.x + h4.y * wd1.y + h4.z * wd1.z + h4.w * wd1.w;
  float xa = r14.x + br4.x, xb = r14.y + br4.y, xc = r14.z + br4.z, xd = r14.w + br4.w;
  float ga = 0.5f * xa * (1.0f + erff(xa * 0.70710678118654752f));
  float gb = 0.5f * xb * (1.0f + erff(xb * 0.70710678118654752f));
  float gc = 0.5f * xc * (1.0f + erff(xc * 0.70710678118654752f));
  float gd = 0.5f * xd * (1.0f + erff(xd * 0.70710678118654752f));
  float s4 = ga * wr2.x + gb * wr2.y + gc * wr2.z + gd * wr2.w;
#pragma unroll
  for (int off = 32; off; off >>= 1) {
    s0 += __shfl_down(s0, off);
    s1 += __shfl_down(s1, off);
    s2 += __shfl_down(s2, off);
    s3 += __shfl_down(s3, off);
    s4 += __shfl_down(s4, off);
  }
  if (lane == 0) {
    head0[row] = s0; head1[row] = s1; dep0[row] = s2; dep1[row] = s3;
    rs[row] = s4 + b_r2[0];
  }
}

// ---------------- K2: MFMA biaffine -> -A into M, plus gold edge sum ----------------
__global__ __launch_bounds__(256) void k2_mfma(const unsigned short* __restrict__ tmp_bf,
    const unsigned short* __restrict__ h_bf, const float* __restrict__ left,
    const float* __restrict__ right, const float* __restrict__ b_bilin,
    const float* __restrict__ head0, const float* __restrict__ head1,
    const float* __restrict__ dep0, const float* __restrict__ dep1,
    float* __restrict__ M, float* __restrict__ gold) {
  __shared__ float red[256];
  int lane = threadIdx.x & 63, w = threadIdx.x >> 6;
  int b = blockIdx.z;
  int i0 = blockIdx.y * 64, j0 = blockIdx.x * 64;
  int arow = i0 + w * 16 + (lane & 15);
  int kof = (lane >> 4) * 8;
  const unsigned short* tb = tmp_bf + (size_t)b * NN * 512;
  const unsigned short* hb = h_bf + (size_t)b * NN * 256;
  f32x4 acc0[4] = {}, acc1[4] = {};
  const unsigned short* ap = tb + (size_t)arow * 512 + kof;
  const unsigned short* bp = hb + (size_t)(j0 + (lane & 15)) * 256 + kof;
#pragma unroll
  for (int kk = 0; kk < 8; ++kk) {
    bf16x8 a0 = *(const bf16x8*)(ap + kk * 32);
    bf16x8 a1 = *(const bf16x8*)(ap + 256 + kk * 32);
#pragma unroll
    for (int t = 0; t < 4; ++t) {
      bf16x8 bfr = *(const bf16x8*)(bp + (size_t)t * 16 * 256 + kk * 32);
      acc0[t] = __builtin_amdgcn_mfma_f32_16x16x32_bf16(a0, bfr, acc0[t], 0, 0, 0);
      acc1[t] = __builtin_amdgcn_mfma_f32_16x16x32_bf16(a1, bfr, acc1[t], 0, 0, 0);
    }
  }
  float bb0 = b_bilin[0], bb1 = b_bilin[1];
  int r0 = i0 + w * 16 + (lane >> 4) * 4;
  int cb = lane & 15;
  float d0a[4], d1a[4];
#pragma unroll
  for (int t = 0; t < 4; ++t) {
    int j = j0 + 16 * t + cb;
    d0a[t] = dep0[b * NN + j];
    d1a[t] = dep1[b * NN + j];
  }
  size_t Mb = (size_t)b * NN * NN;
  float gsum = 0.f;
#pragma unroll
  for (int q = 0; q < 4; ++q) {
    int i = r0 + q;
    float h0 = head0[b * NN + i], h1 = head1[b * NN + i];
#pragma unroll
    for (int t = 0; t < 4; ++t) {
      int j = j0 + 16 * t + cb;
      size_t off = Mb + (size_t)i * NN + j;
      float c0 = acc0[t][q] + h0 + d0a[t] + bb0;
      float c1 = acc1[t][q] + h1 + d1a[t] + bb1;
      gsum += c0 * left[off] + c1 * right[off];
      M[off] = -(__expf(c0) + __expf(c1));
    }
  }
  red[threadIdx.x] = gsum;
  __syncthreads();
#pragma unroll
  for (int s = 128; s; s >>= 1) { if (threadIdx.x < s) red[threadIdx.x] += red[threadIdx.x + s]; __syncthreads(); }
  if (threadIdx.x == 0) atomicAdd(&gold[b], red[0]);
}

// ---------------- K3: column sums -> diag, row0 = exp(root_scores) ----------------
__global__ __launch_bounds__(256) void k3_colsum(float* __restrict__ M, const float* __restrict__ rs) {
  int j = blockIdx.x * 256 + threadIdx.x;
  int b = blockIdx.y;
  float* Mb = M + (size_t)b * NN * NN;
  float s = 0.f;
#pragma unroll 8
  for (int i = 0; i < NN; ++i) s += Mb[(size_t)i * NN + j];
  Mb[(size_t)j * NN + j] -= s;          // += colsum  (M holds -A, s = -colsum)
  Mb[j] = expf(rs[b * NN + j]);         // row 0 replacement
}

// ---------------- K4a: exact LU factor of the first 64x64 block ----------------
__global__ __launch_bounds__(256) void k4a_diag0(float* __restrict__ M,
    float* __restrict__ slog, int* __restrict__ negc, int* __restrict__ zerc) {
  __shared__ float T[64][65];
  __shared__ float red[256];
  __shared__ int redi[256];
  int b = blockIdx.x, tid = threadIdx.x;
  float* Mb = M + (size_t)b * NN * NN;
  for (int idx = tid; idx < 4096; idx += 256) T[idx >> 6][idx & 63] = Mb[(size_t)(idx >> 6) * NN + (idx & 63)];
  __syncthreads();
  for (int j = 0; j < 63; ++j) {
    float inv = 1.0f / T[j][j];
    int nr = 63 - j;
    for (int idx = tid; idx < nr * nr; idx += 256) {
      int r = j + 1 + idx / nr;
      int c = j + 1 + idx % nr;
      T[r][c] -= T[r][j] * inv * T[j][c];
    }
    __syncthreads();
    if (tid < nr) T[j + 1 + tid][j] *= inv;
    __syncthreads();
  }
  float lf = 0.f; int flg = 0;
  if (tid < 64) {
    float d = T[tid][tid];
    lf = logf(fabsf(d));
    flg = (d < 0.f ? 1 : 0) + (d == 0.f ? (1 << 16) : 0);
  }
  red[tid] = lf; redi[tid] = flg;
  __syncthreads();
#pragma unroll
  for (int s = 128; s; s >>= 1) { if (tid < s) { red[tid] += red[tid + s]; redi[tid] += redi[tid + s]; } __syncthreads(); }
  if (tid == 0) { atomicAdd(&slog[b], red[0]); atomicAdd(&negc[b], redi[0] & 0xffff); atomicAdd(&zerc[b], redi[0] >> 16); }
  __syncthreads();
  for (int idx = tid; idx < 4096; idx += 256) Mb[(size_t)(idx >> 6) * NN + (idx & 63)] = T[idx >> 6][idx & 63];
}

// ---------------- K4b: exact triangular solves for step 0 panels ----------------
__global__ __launch_bounds__(64) void k4b_tsolve0(float* __restrict__ M) {
  __shared__ float U[64][65];
  __shared__ float Tt[64][65];
  __shared__ float invd[64];
  int lane = threadIdx.x;
  int t = blockIdx.x, b = blockIdx.y, mode = blockIdx.z;
  float* Mb = M + (size_t)b * NN * NN;
  for (int rr = 0; rr < 64; ++rr) U[rr][lane] = Mb[(size_t)rr * NN + lane];
  __syncthreads();
  invd[lane] = 1.0f / U[lane][lane];
  if (mode == 0) {
    int i0 = 64 + t * 64;
    for (int rr = 0; rr < 64; ++rr) Tt[rr][lane] = Mb[(size_t)(i0 + rr) * NN + lane];
    __syncthreads();
    float x[64];
#pragma unroll
    for (int j = 0; j < 64; ++j) {
      float a = Tt[lane][j];
#pragma unroll
      for (int tt = 0; tt < j; ++tt) a -= x[tt] * U[tt][j];
      x[j] = a * invd[j];
    }
#pragma unroll
    for (int j = 0; j < 64; ++j) Tt[lane][j] = x[j];
    __syncthreads();
    for (int rr = 0; rr < 64; ++rr) Mb[(size_t)(i0 + rr) * NN + lane] = Tt[rr][lane];
  } else {
    int c0 = 64 + t * 64;
    for (int rr = 0; rr < 64; ++rr) Tt[rr][lane] = Mb[(size_t)rr * NN + c0 + lane];
    __syncthreads();
    float y[64];
#pragma unroll
    for (int j = 0; j < 64; ++j) {
      float a = Tt[j][lane];
#pragma unroll
      for (int tt = 0; tt < j; ++tt) a -= U[j][tt] * y[tt];
      y[j] = a;
    }
#pragma unroll
    for (int j = 0; j < 64; ++j) Tt[j][lane] = y[j];
    __syncthreads();
    for (int rr = 0; rr < 64; ++rr) Mb[(size_t)rr * NN + c0 + lane] = Tt[rr][lane];
  }
}

// ---------------- K5: approximate panel prep for steps >= 1 ----------------
__global__ __launch_bounds__(256) void k5_prep(float* __restrict__ M, int k0, int T,
    float* __restrict__ slog, int* __restrict__ negc, int* __restrict__ zerc) {
  __shared__ float D[64][65];
  __shared__ float Wm[64][65];
  __shared__ float At[64][65];
  __shared__ float invd[64];
  __shared__ float red[256];
  __shared__ int redi[256];
  int tid = threadIdx.x;
  int task = blockIdx.x, b = blockIdx.y;
  float* Mb = M + (size_t)b * NN * NN;
  for (int idx = tid; idx < 4096; idx += 256)
    D[idx >> 6][idx & 63] = Mb[(size_t)(k0 + (idx >> 6)) * NN + k0 + (idx & 63)];
  __syncthreads();
  if (task == 2 * T) {
    float lf = 0.f; int flg = 0;
    if (tid < 64) {
      float d = D[tid][tid];
      lf = logf(fabsf(d));
      flg = (d < 0.f ? 1 : 0) + (d == 0.f ? (1 << 16) : 0);
    }
    red[tid] = lf; redi[tid] = flg;
    __syncthreads();
#pragma unroll
    for (int s = 128; s; s >>= 1) { if (tid < s) { red[tid] += red[tid + s]; redi[tid] += redi[tid + s]; } __syncthreads(); }
    if (tid == 0) { atomicAdd(&slog[b], red[0]); atomicAdd(&negc[b], redi[0] & 0xffff); atomicAdd(&zerc[b], redi[0] >> 16); }
    return;
  }
  if (tid < 64) invd[tid] = 1.0f / D[tid][tid];
  __syncthreads();
  int tx = tid & 15, ty = tid >> 4;
  float acc[4][4] = {};
  if (task < T) {
    int i0 = k0 + 64 + task * 64;
    for (int idx = tid; idx < 4096; idx += 256) {
      int r = idx >> 6, c = idx & 63;
      Wm[r][c] = (r == c) ? invd[r] : ((r < c) ? -D[r][c] * invd[r] * invd[c] : 0.f);
      At[r][c] = Mb[(size_t)(i0 + r) * NN + k0 + c];
    }
    __syncthreads();
    for (int k = 0; k < 64; ++k) {
      float a[4], w[4];
#pragma unroll
      for (int r = 0; r < 4; ++r) a[r] = At[ty * 4 + r][k];
#pragma unroll
      for (int c = 0; c < 4; ++c) w[c] = Wm[k][tx * 4 + c];
#pragma unroll
      for (int r = 0; r < 4; ++r)
#pragma unroll
        for (int c = 0; c < 4; ++c) acc[r][c] += a[r] * w[c];
    }
#pragma unroll
    for (int r = 0; r < 4; ++r)
      *(float4*)&Mb[(size_t)(i0 + ty * 4 + r) * NN + k0 + tx * 4] =
          make_float4(acc[r][0], acc[r][1], acc[r][2], acc[r][3]);
  } else {
    int c0 = k0 + 64 + (task - T) * 64;
    for (int idx = tid; idx < 4096; idx += 256) {
      int r = idx >> 6, c = idx & 63;
      Wm[r][c] = (r == c) ? 1.f : ((r > c) ? -D[r][c] * invd[c] : 0.f);
      At[r][c] = Mb[(size_t)(k0 + r) * NN + c0 + c];
    }
    __syncthreads();
    for (int k = 0; k < 64; ++k) {
      float w[4], a[4];
#pragma unroll
      for (int r = 0; r < 4; ++r) w[r] = Wm[ty * 4 + r][k];
#pragma unroll
      for (int c = 0; c < 4; ++c) a[c] = At[k][tx * 4 + c];
#pragma unroll
      for (int r = 0; r < 4; ++r)
#pragma unroll
        for (int c = 0; c < 4; ++c) acc[r][c] += w[r] * a[c];
    }
#pragma unroll
    for (int r = 0; r < 4; ++r)
      *(float4*)&Mb[(size_t)(k0 + ty * 4 + r) * NN + c0 + tx * 4] =
          make_float4(acc[r][0], acc[r][1], acc[r][2], acc[r][3]);
  }
}

// ---------------- K6: trailing update A22 -= L21 * U12 ----------------
__global__ __launch_bounds__(256) void k6_gemm(float* __restrict__ M, int k0) {
  __shared__ __align__(16) float Al[64][68];
  __shared__ __align__(16) float Bl[64][68];
  int tid = threadIdx.x, tx = tid & 15, ty = tid >> 4;
  int b = blockIdx.z;
  int i0 = k0 + 64 + blockIdx.y * 64;
  int j0 = k0 + 64 + blockIdx.x * 64;
  float* Mb = M + (size_t)b * NN * NN;
  for (int idx = tid; idx < 4096; idx += 256) {
    int r = idx >> 6, c = idx & 63;
    Al[r][c] = Mb[(size_t)(i0 + r) * NN + k0 + c];
    Bl[r][c] = Mb[(size_t)(k0 + r) * NN + j0 + c];
  }
  __syncthreads();
  float acc[4][4] = {};
#pragma unroll
  for (int kk = 0; kk < 64; kk += 4) {
    float4 a4[4], b4[4];
#pragma unroll
    for (int r = 0; r < 4; ++r) a4[r] = *(const float4*)&Al[ty * 4 + r][kk];
#pragma unroll
    for (int q = 0; q < 4; ++q) b4[q] = *(const float4*)&Bl[kk + q][tx * 4];
#pragma unroll
    for (int r = 0; r < 4; ++r) {
      float4 a = a4[r];
      acc[r][0] += a.x * b4[0].x + a.y * b4[1].x + a.z * b4[2].x + a.w * b4[3].x;
      acc[r][1] += a.x * b4[0].y + a.y * b4[1].y + a.z * b4[2].y + a.w * b4[3].y;
      acc[r][2] += a.x * b4[0].z + a.y * b4[1].z + a.z * b4[2].z + a.w * b4[3].z;
      acc[r][3] += a.x * b4[0].w + a.y * b4[1].w + a.z * b4[2].w + a.w * b4[3].w;
    }
  }
#pragma unroll
  for (int r = 0; r < 4; ++r) {
    size_t off = (size_t)(i0 + ty * 4 + r) * NN + j0 + tx * 4;
    float4 cv = *(float4*)&Mb[off];
    cv.x -= acc[r][0]; cv.y -= acc[r][1]; cv.z -= acc[r][2]; cv.w -= acc[r][3];
    *(float4*)&Mb[off] = cv;
  }
}

// ---------------- K7: final loss ----------------
__global__ void k7_final(const float* __restrict__ rs, const int* __restrict__ roots,
    const float* __restrict__ gold_e, const float* __restrict__ slog,
    const int* __restrict__ negc, const int* __restrict__ zerc, float* __restrict__ out) {
  if (threadIdx.x == 0 && blockIdx.x == 0) {
    float s = 0.f;
    for (int b = 0; b < BB; ++b) {
      int root = roots[b];
      float gold = rs[b * NN + root] + gold_e[b];
      float ld = slog[b];
      bool pos = ((negc[b] & 1) == 0) && (zerc[b] == 0);
      float loss = 0.f;
      if (pos && !isnan(ld) && !isnan(gold)) {
        if (gold <= ld) loss = ld - gold;
      }
      if (isnan(loss) || isinf(loss)) loss = 0.f;
      s += loss;
    }
    out[0] = ALPHAC * s / (float)BB;
  }
}

extern "C" void kernel_launch(void* const* d_in, const int* in_sizes, int n_in,
                              void* d_out, int out_size, void* d_ws, size_t ws_size,
                              hipStream_t stream) {
  (void)in_sizes; (void)n_in; (void)out_size; (void)ws_size;
  const float* h_cat  = (const float*)d_in[0];
  const float* left   = (const float*)d_in[1];
  const float* right  = (const float*)d_in[2];
  const int*   roots  = (const int*)d_in[3];
  const float* W_bilin = (const float*)d_in[4];
  const float* b_bilin = (const float*)d_in[5];
  const float* W_head = (const float*)d_in[6];
  const float* W_dep  = (const float*)d_in[7];
  const float* W_r1   = (const float*)d_in[8];
  const float* b_r1   = (const float*)d_in[9];
  const float* W_r2   = (const float*)d_in[10];
  const float* b_r2   = (const float*)d_in[11];

  float* ws = (float*)d_ws;
  unsigned short* tmp_bf = (unsigned short*)(ws + OFF_TMPBF);
  unsigned short* h_bf   = (unsigned short*)(ws + OFF_HBF);
  unsigned short* BT     = (unsigned short*)(ws + OFF_BT);
  float* M     = ws + OFF_M;
  float* r1pre = M;  // alias: consumed by k1b before k2 overwrites M
  float* sm    = ws + OFF_SM;
  float* head0 = sm + O_H0;
  float* head1 = sm + O_H1;
  float* dep0  = sm + O_D0;
  float* dep1  = sm + O_D1;
  float* rs    = sm + O_RS;
  float* gold  = sm + O_GOLD;
  float* slog  = sm + O_SLOG;
  int*   negc  = (int*)(sm + O_NEG);
  int*   zerc  = (int*)(sm + O_ZER);

  hipMemsetAsync(gold, 0, 32 * sizeof(float), stream);  // gold, slog, negc, zerc

  k0_cast<<<2816, 256, 0, stream>>>(h_cat, W_bilin, W_r1, h_bf, BT);
  k1_mfma<<<dim3(12, 128), 256, 0, stream>>>(h_bf, BT, tmp_bf, r1pre);
  k1b_rowscal<<<2048, 256, 0, stream>>>(h_cat, W_head, W_dep, b_r1, W_r2, b_r2, r1pre,
                                        head0, head1, dep0, dep1, rs);
  k2_mfma<<<dim3(16, 16, 8), 256, 0, stream>>>(tmp_bf, h_bf, left, right, b_bilin,
                                               head0, head1, dep0, dep1, M, gold);
  k3_colsum<<<dim3(4, 8), 256, 0, stream>>>(M, rs);
  k4a_diag0<<<8, 256, 0, stream>>>(M, slog, negc, zerc);
  k4b_tsolve0<<<dim3(15, 8, 2), 64, 0, stream>>>(M);
  k6_gemm<<<dim3(15, 15, 8), 256, 0, stream>>>(M, 0);
  for (int s = 1; s <= 15; ++s) {
    int k0 = s * 64, T = 15 - s;
    k5_prep<<<dim3(2 * T + 1, 8), 256, 0, stream>>>(M, k0, T, slog, negc, zerc);
    if (T > 0) k6_gemm<<<dim3(T, T, 8), 256, 0, stream>>>(M, k0);
  }
  k7_final<<<1, 64, 0, stream>>>(rs, roots, gold, slog, negc, zerc, (float*)d_out);
}

// Round 3
// 406.156 us; speedup vs baseline: 3.3901x; 2.3274x over previous
//
#include <hip/hip_runtime.h>
#include <math.h>

#define BB 8
#define NN 1024
#define HH 256
#define ALPHAC 0.25f

typedef short bf16x8 __attribute__((ext_vector_type(8)));
typedef float f32x4 __attribute__((ext_vector_type(4)));

__device__ inline unsigned short f2bf(float x) {
  unsigned u = __builtin_bit_cast(unsigned, x);
  unsigned r = (u + 0x7fffu + ((u >> 16) & 1u)) >> 16;
  return (unsigned short)r;
}

// symmetric permutation 0 <-> 1023 (det-invariant): moves the non-dominant
// root row/col into the last 64x64 block so ALL leading blocks are
// diagonally dominant and the diag-Neumann elimination applies everywhere.
__device__ inline int prm(int i) { return i == 0 ? 1023 : (i == 1023 ? 0 : i); }

// ---------------- workspace layout (float offsets) ----------------
static const size_t OFF_TMPBF = 0;          // tmp_bf [8192][512] bf16
static const size_t OFF_HBF   = 2097152;    // h_bf   [8192][256] bf16
static const size_t OFF_BT    = 3145728;    // BT     [768][256]  bf16
static const size_t OFF_M     = 4194304;    // M      [8][1024][1024] f32
static const size_t SZ_M      = (size_t)8 * 1024 * 1024;
static const size_t OFF_SM    = OFF_M + SZ_M;
static const size_t O_H0 = 0, O_H1 = 8192, O_D0 = 16384, O_D1 = 24576, O_RS = 32768;
static const size_t O_GOLD = 40960, O_SLOG = 40968, O_NEG = 40976, O_ZER = 40984;

// ---------------- K0: cast h -> bf16, build BT (weights, bf16, B^T layout) ----------------
__global__ __launch_bounds__(256) void k0_cast(const float* __restrict__ h_cat,
    const float* __restrict__ Wb, const float* __restrict__ Wr1,
    unsigned short* __restrict__ h_bf, unsigned short* __restrict__ BT) {
  int bid = blockIdx.x, tid = threadIdx.x;
  if (bid < 2048) {
    int idx4 = bid * 256 + tid;
    float4 v = *(const float4*)&h_cat[(size_t)idx4 * 4];
    ushort4 o;
    o.x = f2bf(v.x); o.y = f2bf(v.y); o.z = f2bf(v.z); o.w = f2bf(v.w);
    *(ushort4*)&h_bf[(size_t)idx4 * 4] = o;
  } else if (bid < 2560) {
    int idx = (bid - 2048) * 256 + tid;
    int c = idx >> 8, h = idx & 255;
    BT[(size_t)c * 256 + h] = f2bf(Wb[(size_t)(c >> 8) * 65536 + (size_t)h * 256 + (c & 255)]);
  } else {
    int idx = (bid - 2560) * 256 + tid;
    int c = idx >> 8, h = idx & 255;
    BT[(size_t)(512 + c) * 256 + h] = f2bf(Wr1[(size_t)c * 256 + h]);
  }
}

// ---------------- K1: MFMA GEMM  C[8192][768] = h_bf * BT^T ----------------
__global__ __launch_bounds__(256) void k1_mfma(const unsigned short* __restrict__ h_bf,
    const unsigned short* __restrict__ BT, unsigned short* __restrict__ tmp_bf,
    float* __restrict__ r1pre) {
  int lane = threadIdx.x & 63, w = threadIdx.x >> 6;
  int m0 = blockIdx.y * 64 + w * 16;
  int n0 = blockIdx.x * 64;
  int arow = m0 + (lane & 15);
  int kof = (lane >> 4) * 8;
  f32x4 acc[4] = {};
  const unsigned short* ap = h_bf + (size_t)arow * 256 + kof;
  const unsigned short* bp = BT + (size_t)(n0 + (lane & 15)) * 256 + kof;
#pragma unroll
  for (int kk = 0; kk < 8; ++kk) {
    bf16x8 a = *(const bf16x8*)(ap + kk * 32);
#pragma unroll
    for (int t = 0; t < 4; ++t) {
      bf16x8 b = *(const bf16x8*)(bp + (size_t)t * 16 * 256 + kk * 32);
      acc[t] = __builtin_amdgcn_mfma_f32_16x16x32_bf16(a, b, acc[t], 0, 0, 0);
    }
  }
  int r0 = m0 + (lane >> 4) * 4;
  int cb = lane & 15;
  if (n0 < 512) {
#pragma unroll
    for (int t = 0; t < 4; ++t)
#pragma unroll
      for (int q = 0; q < 4; ++q)
        tmp_bf[(size_t)(r0 + q) * 512 + n0 + 16 * t + cb] = f2bf(acc[t][q]);
  } else {
#pragma unroll
    for (int t = 0; t < 4; ++t)
#pragma unroll
      for (int q = 0; q < 4; ++q)
        r1pre[(size_t)(r0 + q) * 256 + (n0 - 512) + 16 * t + cb] = acc[t][q];
  }
}

// ---------------- K1b: head/dep scalars + root scores (GELU) ----------------
__global__ __launch_bounds__(256) void k1b_rowscal(const float* __restrict__ h_cat,
    const float* __restrict__ W_head, const float* __restrict__ W_dep,
    const float* __restrict__ b_r1, const float* __restrict__ W_r2,
    const float* __restrict__ b_r2, const float* __restrict__ r1pre,
    float* __restrict__ head0, float* __restrict__ head1,
    float* __restrict__ dep0, float* __restrict__ dep1, float* __restrict__ rs) {
  int wave = threadIdx.x >> 6;
  int lane = threadIdx.x & 63;
  int row = blockIdx.x * 4 + wave;
  float4 h4  = *(const float4*)&h_cat[(size_t)row * 256 + lane * 4];
  float4 wh0 = *(const float4*)&W_head[lane * 4];
  float4 wh1 = *(const float4*)&W_head[256 + lane * 4];
  float4 wd0 = *(const float4*)&W_dep[lane * 4];
  float4 wd1 = *(const float4*)&W_dep[256 + lane * 4];
  float4 r14 = *(const float4*)&r1pre[(size_t)row * 256 + lane * 4];
  float4 br4 = *(const float4*)&b_r1[lane * 4];
  float4 wr2 = *(const float4*)&W_r2[lane * 4];
  float s0 = h4.x * wh0.x + h4.y * wh0.y + h4.z * wh0.z + h4.w * wh0.w;
  float s1 = h4.x * wh1.x + h4.y * wh1.y + h4.z * wh1.z + h4.w * wh1.w;
  float s2 = h4.x * wd0.x + h4.y * wd0.y + h4.z * wd0.z + h4.w * wd0.w;
  float s3 = h4.x * wd1.x + h4.y * wd1.y + h4.z * wd1.z + h4.w * wd1.w;
  float xa = r14.x + br4.x, xb = r14.y + br4.y, xc = r14.z + br4.z, xd = r14.w + br4.w;
  float ga = 0.5f * xa * (1.0f + erff(xa * 0.70710678118654752f));
  float gb = 0.5f * xb * (1.0f + erff(xb * 0.70710678118654752f));
  float gc = 0.5f * xc * (1.0f + erff(xc * 0.70710678118654752f));
  float gd = 0.5f * xd * (1.0f + erff(xd * 0.70710678118654752f));
  float s4 = ga * wr2.x + gb * wr2.y + gc * wr2.z + gd * wr2.w;
#pragma unroll
  for (int off = 32; off; off >>= 1) {
    s0 += __shfl_down(s0, off);
    s1 += __shfl_down(s1, off);
    s2 += __shfl_down(s2, off);
    s3 += __shfl_down(s3, off);
    s4 += __shfl_down(s4, off);
  }
  if (lane == 0) {
    head0[row] = s0; head1[row] = s1; dep0[row] = s2; dep1[row] = s3;
    rs[row] = s4 + b_r2[0];
  }
}

// ---------------- K2: MFMA biaffine -> -A into M (permuted), plus gold edge sum ----------------
__global__ __launch_bounds__(256) void k2_mfma(const unsigned short* __restrict__ tmp_bf,
    const unsigned short* __restrict__ h_bf, const float* __restrict__ left,
    const float* __restrict__ right, const float* __restrict__ b_bilin,
    const float* __restrict__ head0, const float* __restrict__ head1,
    const float* __restrict__ dep0, const float* __restrict__ dep1,
    float* __restrict__ M, float* __restrict__ gold) {
  __shared__ float red[256];
  int lane = threadIdx.x & 63, w = threadIdx.x >> 6;
  int b = blockIdx.z;
  int i0 = blockIdx.y * 64, j0 = blockIdx.x * 64;
  int arow = i0 + w * 16 + (lane & 15);
  int kof = (lane >> 4) * 8;
  const unsigned short* tb = tmp_bf + (size_t)b * NN * 512;
  const unsigned short* hb = h_bf + (size_t)b * NN * 256;
  f32x4 acc0[4] = {}, acc1[4] = {};
  const unsigned short* ap = tb + (size_t)arow * 512 + kof;
  const unsigned short* bp = hb + (size_t)(j0 + (lane & 15)) * 256 + kof;
#pragma unroll
  for (int kk = 0; kk < 8; ++kk) {
    bf16x8 a0 = *(const bf16x8*)(ap + kk * 32);
    bf16x8 a1 = *(const bf16x8*)(ap + 256 + kk * 32);
#pragma unroll
    for (int t = 0; t < 4; ++t) {
      bf16x8 bfr = *(const bf16x8*)(bp + (size_t)t * 16 * 256 + kk * 32);
      acc0[t] = __builtin_amdgcn_mfma_f32_16x16x32_bf16(a0, bfr, acc0[t], 0, 0, 0);
      acc1[t] = __builtin_amdgcn_mfma_f32_16x16x32_bf16(a1, bfr, acc1[t], 0, 0, 0);
    }
  }
  float bb0 = b_bilin[0], bb1 = b_bilin[1];
  int r0 = i0 + w * 16 + (lane >> 4) * 4;
  int cb = lane & 15;
  float d0a[4], d1a[4];
#pragma unroll
  for (int t = 0; t < 4; ++t) {
    int j = j0 + 16 * t + cb;
    d0a[t] = dep0[b * NN + j];
    d1a[t] = dep1[b * NN + j];
  }
  size_t Mb = (size_t)b * NN * NN;
  float gsum = 0.f;
#pragma unroll
  for (int q = 0; q < 4; ++q) {
    int i = r0 + q;
    float h0 = head0[b * NN + i], h1 = head1[b * NN + i];
#pragma unroll
    for (int t = 0; t < 4; ++t) {
      int j = j0 + 16 * t + cb;
      size_t offlr = Mb + (size_t)i * NN + j;
      float c0 = acc0[t][q] + h0 + d0a[t] + bb0;
      float c1 = acc1[t][q] + h1 + d1a[t] + bb1;
      gsum += c0 * left[offlr] + c1 * right[offlr];
      M[Mb + (size_t)prm(i) * NN + prm(j)] = -(__expf(c0) + __expf(c1));
    }
  }
  red[threadIdx.x] = gsum;
  __syncthreads();
#pragma unroll
  for (int s = 128; s; s >>= 1) { if (threadIdx.x < s) red[threadIdx.x] += red[threadIdx.x + s]; __syncthreads(); }
  if (threadIdx.x == 0) atomicAdd(&gold[b], red[0]);
}

// ---------------- K3: column sums -> diag add; permuted row 1023 = exp(root_scores) ----------------
__global__ __launch_bounds__(256) void k3_colsum(float* __restrict__ M, const float* __restrict__ rs) {
  int j = blockIdx.x * 256 + threadIdx.x;   // permuted column index
  int b = blockIdx.y;
  float* Mb = M + (size_t)b * NN * NN;
  float s0 = 0.f, s1 = 0.f, s2 = 0.f, s3 = 0.f;
  for (int i = 0; i < NN; i += 4) {
    s0 += Mb[(size_t)i * NN + j];
    s1 += Mb[(size_t)(i + 1) * NN + j];
    s2 += Mb[(size_t)(i + 2) * NN + j];
    s3 += Mb[(size_t)(i + 3) * NN + j];
  }
  float s = (s0 + s1) + (s2 + s3);
  Mb[(size_t)j * NN + j] -= s;                       // diag += colsum  (M holds -A)
  Mb[(size_t)1023 * NN + j] = expf(rs[b * NN + prm(j)]);  // permuted row 0 -> row 1023
}

// ---------------- K6: Schur step  A22 -= A21 * diag(D)^-1 * A12  (bf16 MFMA) ----------------
// block (0,0) also accumulates sum(log|diag|) of the current pivot block.
__global__ __launch_bounds__(256) void k6_schur(float* __restrict__ M, int k0,
    float* __restrict__ slog, int* __restrict__ negc, int* __restrict__ zerc) {
  __shared__ __align__(16) unsigned short As[64][72];
  __shared__ __align__(16) unsigned short Bt[64][72];
  __shared__ float rd[64];
  int tid = threadIdx.x;
  int b = blockIdx.z;
  float* Mb = M + (size_t)b * NN * NN;
  float lf = 0.f; int flg = 0;
  if (tid < 64) {
    float d = Mb[(size_t)(k0 + tid) * NN + k0 + tid];
    rd[tid] = 1.0f / d;
    lf = logf(fabsf(d));
    flg = (d < 0.f ? 1 : 0) + (d == 0.f ? (1 << 16) : 0);
  }
  if (blockIdx.x == 0 && blockIdx.y == 0 && tid < 64) {
#pragma unroll
    for (int off = 32; off; off >>= 1) { lf += __shfl_down(lf, off); flg += __shfl_down(flg, off); }
    if (tid == 0) { atomicAdd(&slog[b], lf); atomicAdd(&negc[b], flg & 0xffff); atomicAdd(&zerc[b], flg >> 16); }
  }
  __syncthreads();
  int i0 = k0 + 64 + blockIdx.y * 64;
  int j0 = k0 + 64 + blockIdx.x * 64;
#pragma unroll
  for (int it = 0; it < 4; ++it) {
    int idx = tid + it * 256;          // 1024 float4 groups
    int r = idx >> 4, c4 = (idx & 15) * 4;
    float4 v = *(const float4*)&Mb[(size_t)(i0 + r) * NN + k0 + c4];
    As[r][c4 + 0] = f2bf(v.x * rd[c4 + 0]);
    As[r][c4 + 1] = f2bf(v.y * rd[c4 + 1]);
    As[r][c4 + 2] = f2bf(v.z * rd[c4 + 2]);
    As[r][c4 + 3] = f2bf(v.w * rd[c4 + 3]);
    float4 u = *(const float4*)&Mb[(size_t)(k0 + r) * NN + j0 + c4];
    Bt[c4 + 0][r] = f2bf(u.x);
    Bt[c4 + 1][r] = f2bf(u.y);
    Bt[c4 + 2][r] = f2bf(u.z);
    Bt[c4 + 3][r] = f2bf(u.w);
  }
  __syncthreads();
  int lane = tid & 63, w = tid >> 6;
  int rbase = w * 16;
  f32x4 acc[4] = {};
#pragma unroll
  for (int kk = 0; kk < 2; ++kk) {
    bf16x8 a = *(const bf16x8*)&As[rbase + (lane & 15)][(lane >> 4) * 8 + kk * 32];
#pragma unroll
    for (int t = 0; t < 4; ++t) {
      bf16x8 bb = *(const bf16x8*)&Bt[t * 16 + (lane & 15)][(lane >> 4) * 8 + kk * 32];
      acc[t] = __builtin_amdgcn_mfma_f32_16x16x32_bf16(a, bb, acc[t], 0, 0, 0);
    }
  }
  int rr = rbase + (lane >> 4) * 4;
  int cb = lane & 15;
#pragma unroll
  for (int t = 0; t < 4; ++t)
#pragma unroll
    for (int q = 0; q < 4; ++q)
      Mb[(size_t)(i0 + rr + q) * NN + j0 + 16 * t + cb] -= acc[t][q];
}

// ---------------- K9: exact in-LDS LU of the last 64x64 block ----------------
__global__ __launch_bounds__(256) void k9_last(float* __restrict__ M,
    float* __restrict__ slog, int* __restrict__ negc, int* __restrict__ zerc) {
  __shared__ float T[64][65];
  int b = blockIdx.x, tid = threadIdx.x;
  const float* Mb = M + (size_t)b * NN * NN;
  for (int idx = tid; idx < 4096; idx += 256)
    T[idx >> 6][idx & 63] = Mb[(size_t)(960 + (idx >> 6)) * NN + 960 + (idx & 63)];
  __syncthreads();
  for (int j = 0; j < 63; ++j) {
    float inv = 1.0f / T[j][j];
#pragma unroll
    for (int it = 0; it < 16; ++it) {
      int idx = tid + it * 256;
      int r = idx >> 6, c = idx & 63;
      if (r > j && c > j) T[r][c] -= T[r][j] * inv * T[j][c];
    }
    __syncthreads();
  }
  float lf = 0.f; int flg = 0;
  if (tid < 64) {
    float d = T[tid][tid];
    lf = logf(fabsf(d));
    flg = (d < 0.f ? 1 : 0) + (d == 0.f ? (1 << 16) : 0);
#pragma unroll
    for (int off = 32; off; off >>= 1) { lf += __shfl_down(lf, off); flg += __shfl_down(flg, off); }
    if (tid == 0) { atomicAdd(&slog[b], lf); atomicAdd(&negc[b], flg & 0xffff); atomicAdd(&zerc[b], flg >> 16); }
  }
}

// ---------------- K7: final loss ----------------
__global__ void k7_final(const float* __restrict__ rs, const int* __restrict__ roots,
    const float* __restrict__ gold_e, const float* __restrict__ slog,
    const int* __restrict__ negc, const int* __restrict__ zerc, float* __restrict__ out) {
  if (threadIdx.x == 0 && blockIdx.x == 0) {
    float s = 0.f;
    for (int b = 0; b < BB; ++b) {
      int root = roots[b];
      float gold = rs[b * NN + root] + gold_e[b];
      float ld = slog[b];
      bool pos = ((negc[b] & 1) == 0) && (zerc[b] == 0);
      float loss = 0.f;
      if (pos && !isnan(ld) && !isnan(gold)) {
        if (gold <= ld) loss = ld - gold;
      }
      if (isnan(loss) || isinf(loss)) loss = 0.f;
      s += loss;
    }
    out[0] = ALPHAC * s / (float)BB;
  }
}

extern "C" void kernel_launch(void* const* d_in, const int* in_sizes, int n_in,
                              void* d_out, int out_size, void* d_ws, size_t ws_size,
                              hipStream_t stream) {
  (void)in_sizes; (void)n_in; (void)out_size; (void)ws_size;
  const float* h_cat  = (const float*)d_in[0];
  const float* left   = (const float*)d_in[1];
  const float* right  = (const float*)d_in[2];
  const int*   roots  = (const int*)d_in[3];
  const float* W_bilin = (const float*)d_in[4];
  const float* b_bilin = (const float*)d_in[5];
  const float* W_head = (const float*)d_in[6];
  const float* W_dep  = (const float*)d_in[7];
  const float* W_r1   = (const float*)d_in[8];
  const float* b_r1   = (const float*)d_in[9];
  const float* W_r2   = (const float*)d_in[10];
  const float* b_r2   = (const float*)d_in[11];

  float* ws = (float*)d_ws;
  unsigned short* tmp_bf = (unsigned short*)(ws + OFF_TMPBF);
  unsigned short* h_bf   = (unsigned short*)(ws + OFF_HBF);
  unsigned short* BT     = (unsigned short*)(ws + OFF_BT);
  float* M     = ws + OFF_M;
  float* r1pre = M;  // alias: consumed by k1b before k2 overwrites M
  float* sm    = ws + OFF_SM;
  float* head0 = sm + O_H0;
  float* head1 = sm + O_H1;
  float* dep0  = sm + O_D0;
  float* dep1  = sm + O_D1;
  float* rs    = sm + O_RS;
  float* gold  = sm + O_GOLD;
  float* slog  = sm + O_SLOG;
  int*   negc  = (int*)(sm + O_NEG);
  int*   zerc  = (int*)(sm + O_ZER);

  hipMemsetAsync(gold, 0, 32 * sizeof(float), stream);  // gold, slog, negc, zerc

  k0_cast<<<2816, 256, 0, stream>>>(h_cat, W_bilin, W_r1, h_bf, BT);
  k1_mfma<<<dim3(12, 128), 256, 0, stream>>>(h_bf, BT, tmp_bf, r1pre);
  k1b_rowscal<<<2048, 256, 0, stream>>>(h_cat, W_head, W_dep, b_r1, W_r2, b_r2, r1pre,
                                        head0, head1, dep0, dep1, rs);
  k2_mfma<<<dim3(16, 16, 8), 256, 0, stream>>>(tmp_bf, h_bf, left, right, b_bilin,
                                               head0, head1, dep0, dep1, M, gold);
  k3_colsum<<<dim3(4, 8), 256, 0, stream>>>(M, rs);
  for (int s = 0; s < 15; ++s)
    k6_schur<<<dim3(15 - s, 15 - s, 8), 256, 0, stream>>>(M, s * 64, slog, negc, zerc);
  k9_last<<<8, 256, 0, stream>>>(M, slog, negc, zerc);
  k7_final<<<1, 64, 0, stream>>>(rs, roots, gold, slog, negc, zerc, (float*)d_out);
}

// Round 4
// 328.874 us; speedup vs baseline: 4.1867x; 1.2350x over previous
//
#include <hip/hip_runtime.h>
#include <math.h>

#define BB 8
#define NN 1024
#define HH 256
#define ALPHAC 0.25f

typedef short bf16x8 __attribute__((ext_vector_type(8)));
typedef float f32x4 __attribute__((ext_vector_type(4)));

__device__ inline unsigned short f2bf(float x) {
  unsigned u = __builtin_bit_cast(unsigned, x);
  unsigned r = (u + 0x7fffu + ((u >> 16) & 1u)) >> 16;
  return (unsigned short)r;
}

// symmetric permutation 0 <-> 1023 (det-invariant): moves the non-dominant
// root row/col into the last 64x64 block so ALL leading blocks are
// diagonally dominant and the diag-Neumann elimination applies everywhere.
__device__ inline int prm(int i) { return i == 0 ? 1023 : (i == 1023 ? 0 : i); }

// ---------------- workspace layout (float offsets) ----------------
static const size_t OFF_TMPBF = 0;          // tmp_bf [8192][512] bf16
static const size_t OFF_HBF   = 2097152;    // h_bf   [8192][256] bf16
static const size_t OFF_BT    = 3145728;    // BT     [768][256]  bf16
static const size_t OFF_M     = 4194304;    // M      [8][1024][1024] f32
static const size_t SZ_M      = (size_t)8 * 1024 * 1024;
static const size_t OFF_SM    = OFF_M + SZ_M;
static const size_t O_H0 = 0, O_H1 = 8192, O_D0 = 16384, O_D1 = 24576, O_RS = 32768;
static const size_t O_GOLD = 40960, O_SLOG = 40968, O_NEG = 40976, O_ZER = 40984;
static const size_t O_CS   = 40992;         // colsum [8][1024] f32 (memset with flags)

// ---------------- K0: cast h -> bf16, build BT (weights, bf16, B^T layout) ----------------
__global__ __launch_bounds__(256) void k0_cast(const float* __restrict__ h_cat,
    const float* __restrict__ Wb, const float* __restrict__ Wr1,
    unsigned short* __restrict__ h_bf, unsigned short* __restrict__ BT) {
  int bid = blockIdx.x, tid = threadIdx.x;
  if (bid < 2048) {
    int idx4 = bid * 256 + tid;
    float4 v = *(const float4*)&h_cat[(size_t)idx4 * 4];
    ushort4 o;
    o.x = f2bf(v.x); o.y = f2bf(v.y); o.z = f2bf(v.z); o.w = f2bf(v.w);
    *(ushort4*)&h_bf[(size_t)idx4 * 4] = o;
  } else if (bid < 2560) {
    int idx = (bid - 2048) * 256 + tid;
    int c = idx >> 8, h = idx & 255;
    BT[(size_t)c * 256 + h] = f2bf(Wb[(size_t)(c >> 8) * 65536 + (size_t)h * 256 + (c & 255)]);
  } else {
    int idx = (bid - 2560) * 256 + tid;
    int c = idx >> 8, h = idx & 255;
    BT[(size_t)(512 + c) * 256 + h] = f2bf(Wr1[(size_t)c * 256 + h]);
  }
}

// ---------------- K1: MFMA GEMM  C[8192][768] = h_bf * BT^T ----------------
__global__ __launch_bounds__(256) void k1_mfma(const unsigned short* __restrict__ h_bf,
    const unsigned short* __restrict__ BT, unsigned short* __restrict__ tmp_bf,
    float* __restrict__ r1pre) {
  int lane = threadIdx.x & 63, w = threadIdx.x >> 6;
  int m0 = blockIdx.y * 64 + w * 16;
  int n0 = blockIdx.x * 64;
  int arow = m0 + (lane & 15);
  int kof = (lane >> 4) * 8;
  f32x4 acc[4] = {};
  const unsigned short* ap = h_bf + (size_t)arow * 256 + kof;
  const unsigned short* bp = BT + (size_t)(n0 + (lane & 15)) * 256 + kof;
#pragma unroll
  for (int kk = 0; kk < 8; ++kk) {
    bf16x8 a = *(const bf16x8*)(ap + kk * 32);
#pragma unroll
    for (int t = 0; t < 4; ++t) {
      bf16x8 b = *(const bf16x8*)(bp + (size_t)t * 16 * 256 + kk * 32);
      acc[t] = __builtin_amdgcn_mfma_f32_16x16x32_bf16(a, b, acc[t], 0, 0, 0);
    }
  }
  int r0 = m0 + (lane >> 4) * 4;
  int cb = lane & 15;
  if (n0 < 512) {
#pragma unroll
    for (int t = 0; t < 4; ++t)
#pragma unroll
      for (int q = 0; q < 4; ++q)
        tmp_bf[(size_t)(r0 + q) * 512 + n0 + 16 * t + cb] = f2bf(acc[t][q]);
  } else {
#pragma unroll
    for (int t = 0; t < 4; ++t)
#pragma unroll
      for (int q = 0; q < 4; ++q)
        r1pre[(size_t)(r0 + q) * 256 + (n0 - 512) + 16 * t + cb] = acc[t][q];
  }
}

// ---------------- K1b: head/dep scalars + root scores (GELU) ----------------
__global__ __launch_bounds__(256) void k1b_rowscal(const float* __restrict__ h_cat,
    const float* __restrict__ W_head, const float* __restrict__ W_dep,
    const float* __restrict__ b_r1, const float* __restrict__ W_r2,
    const float* __restrict__ b_r2, const float* __restrict__ r1pre,
    float* __restrict__ head0, float* __restrict__ head1,
    float* __restrict__ dep0, float* __restrict__ dep1, float* __restrict__ rs) {
  int wave = threadIdx.x >> 6;
  int lane = threadIdx.x & 63;
  int row = blockIdx.x * 4 + wave;
  float4 h4  = *(const float4*)&h_cat[(size_t)row * 256 + lane * 4];
  float4 wh0 = *(const float4*)&W_head[lane * 4];
  float4 wh1 = *(const float4*)&W_head[256 + lane * 4];
  float4 wd0 = *(const float4*)&W_dep[lane * 4];
  float4 wd1 = *(const float4*)&W_dep[256 + lane * 4];
  float4 r14 = *(const float4*)&r1pre[(size_t)row * 256 + lane * 4];
  float4 br4 = *(const float4*)&b_r1[lane * 4];
  float4 wr2 = *(const float4*)&W_r2[lane * 4];
  float s0 = h4.x * wh0.x + h4.y * wh0.y + h4.z * wh0.z + h4.w * wh0.w;
  float s1 = h4.x * wh1.x + h4.y * wh1.y + h4.z * wh1.z + h4.w * wh1.w;
  float s2 = h4.x * wd0.x + h4.y * wd0.y + h4.z * wd0.z + h4.w * wd0.w;
  float s3 = h4.x * wd1.x + h4.y * wd1.y + h4.z * wd1.z + h4.w * wd1.w;
  float xa = r14.x + br4.x, xb = r14.y + br4.y, xc = r14.z + br4.z, xd = r14.w + br4.w;
  float ga = 0.5f * xa * (1.0f + erff(xa * 0.70710678118654752f));
  float gb = 0.5f * xb * (1.0f + erff(xb * 0.70710678118654752f));
  float gc = 0.5f * xc * (1.0f + erff(xc * 0.70710678118654752f));
  float gd = 0.5f * xd * (1.0f + erff(xd * 0.70710678118654752f));
  float s4 = ga * wr2.x + gb * wr2.y + gc * wr2.z + gd * wr2.w;
#pragma unroll
  for (int off = 32; off; off >>= 1) {
    s0 += __shfl_down(s0, off);
    s1 += __shfl_down(s1, off);
    s2 += __shfl_down(s2, off);
    s3 += __shfl_down(s3, off);
    s4 += __shfl_down(s4, off);
  }
  if (lane == 0) {
    head0[row] = s0; head1[row] = s1; dep0[row] = s2; dep1[row] = s3;
    rs[row] = s4 + b_r2[0];
  }
}

// ---------------- K2: MFMA biaffine -> -A into M (permuted) + gold + colsum ----------------
__global__ __launch_bounds__(256) void k2_mfma(const unsigned short* __restrict__ tmp_bf,
    const unsigned short* __restrict__ h_bf, const float* __restrict__ left,
    const float* __restrict__ right, const float* __restrict__ b_bilin,
    const float* __restrict__ head0, const float* __restrict__ head1,
    const float* __restrict__ dep0, const float* __restrict__ dep1,
    float* __restrict__ M, float* __restrict__ gold, float* __restrict__ colsum) {
  __shared__ float red[256];
  int lane = threadIdx.x & 63, w = threadIdx.x >> 6;
  int b = blockIdx.z;
  int i0 = blockIdx.y * 64, j0 = blockIdx.x * 64;
  int arow = i0 + w * 16 + (lane & 15);
  int kof = (lane >> 4) * 8;
  const unsigned short* tb = tmp_bf + (size_t)b * NN * 512;
  const unsigned short* hb = h_bf + (size_t)b * NN * 256;
  f32x4 acc0[4] = {}, acc1[4] = {};
  const unsigned short* ap = tb + (size_t)arow * 512 + kof;
  const unsigned short* bp = hb + (size_t)(j0 + (lane & 15)) * 256 + kof;
#pragma unroll
  for (int kk = 0; kk < 8; ++kk) {
    bf16x8 a0 = *(const bf16x8*)(ap + kk * 32);
    bf16x8 a1 = *(const bf16x8*)(ap + 256 + kk * 32);
#pragma unroll
    for (int t = 0; t < 4; ++t) {
      bf16x8 bfr = *(const bf16x8*)(bp + (size_t)t * 16 * 256 + kk * 32);
      acc0[t] = __builtin_amdgcn_mfma_f32_16x16x32_bf16(a0, bfr, acc0[t], 0, 0, 0);
      acc1[t] = __builtin_amdgcn_mfma_f32_16x16x32_bf16(a1, bfr, acc1[t], 0, 0, 0);
    }
  }
  float bb0 = b_bilin[0], bb1 = b_bilin[1];
  int r0 = i0 + w * 16 + (lane >> 4) * 4;
  int cb = lane & 15;
  float d0a[4], d1a[4];
#pragma unroll
  for (int t = 0; t < 4; ++t) {
    int j = j0 + 16 * t + cb;
    d0a[t] = dep0[b * NN + j];
    d1a[t] = dep1[b * NN + j];
  }
  size_t Mb = (size_t)b * NN * NN;
  float gsum = 0.f;
  float csum[4] = {};
#pragma unroll
  for (int q = 0; q < 4; ++q) {
    int i = r0 + q;
    float h0 = head0[b * NN + i], h1 = head1[b * NN + i];
#pragma unroll
    for (int t = 0; t < 4; ++t) {
      int j = j0 + 16 * t + cb;
      size_t offlr = Mb + (size_t)i * NN + j;
      float c0 = acc0[t][q] + h0 + d0a[t] + bb0;
      float c1 = acc1[t][q] + h1 + d1a[t] + bb1;
      gsum += c0 * left[offlr] + c1 * right[offlr];
      float aexp = __expf(c0) + __expf(c1);
      csum[t] += aexp;
      M[Mb + (size_t)prm(i) * NN + prm(j)] = -aexp;
    }
  }
  // ---- column-sum reduction: 4 row-slots/wave via shfl, 4 waves via LDS ----
#pragma unroll
  for (int t = 0; t < 4; ++t) {
    float v = csum[t];
    v += __shfl_down(v, 32);
    v += __shfl_down(v, 16);
    if (lane < 16) red[w * 64 + t * 16 + lane] = v;
  }
  __syncthreads();
  if (threadIdx.x < 64) {
    int t = threadIdx.x >> 4, c = threadIdx.x & 15;
    float s = red[t * 16 + c] + red[64 + t * 16 + c] + red[128 + t * 16 + c] + red[192 + t * 16 + c];
    atomicAdd(&colsum[b * NN + prm(j0 + 16 * t + c)], s);
  }
  __syncthreads();
  red[threadIdx.x] = gsum;
  __syncthreads();
#pragma unroll
  for (int s = 128; s; s >>= 1) { if (threadIdx.x < s) red[threadIdx.x] += red[threadIdx.x + s]; __syncthreads(); }
  if (threadIdx.x == 0) atomicAdd(&gold[b], red[0]);
}

// ---------------- K3b: diag += colsum; permuted row 1023 = exp(root_scores) ----------------
__global__ __launch_bounds__(1024) void k3b_diag(float* __restrict__ M,
    const float* __restrict__ colsum, const float* __restrict__ rs) {
  int j = threadIdx.x;          // permuted column index
  int b = blockIdx.x;
  float* Mb = M + (size_t)b * NN * NN;
  float d = Mb[(size_t)j * NN + j] + colsum[b * NN + j];
  if (j != 1023) Mb[(size_t)j * NN + j] = d;
  Mb[(size_t)1023 * NN + j] = expf(rs[b * NN + prm(j)]);
}

// ---------------- K6: Schur step  A22 -= A21 * diag(D)^-1 * A12  (bf16 MFMA) ----------------
__global__ __launch_bounds__(256) void k6_schur(float* __restrict__ M, int k0,
    float* __restrict__ slog, int* __restrict__ negc, int* __restrict__ zerc) {
  __shared__ __align__(16) unsigned short As[64][72];
  __shared__ __align__(16) unsigned short Bt[64][72];
  __shared__ float rd[64];
  int tid = threadIdx.x;
  int b = blockIdx.z;
  float* Mb = M + (size_t)b * NN * NN;
  float lf = 0.f; int flg = 0;
  if (tid < 64) {
    float d = Mb[(size_t)(k0 + tid) * NN + k0 + tid];
    rd[tid] = 1.0f / d;
    lf = logf(fabsf(d));
    flg = (d < 0.f ? 1 : 0) + (d == 0.f ? (1 << 16) : 0);
  }
  if (blockIdx.x == 0 && blockIdx.y == 0 && tid < 64) {
#pragma unroll
    for (int off = 32; off; off >>= 1) { lf += __shfl_down(lf, off); flg += __shfl_down(flg, off); }
    if (tid == 0) { atomicAdd(&slog[b], lf); atomicAdd(&negc[b], flg & 0xffff); atomicAdd(&zerc[b], flg >> 16); }
  }
  __syncthreads();
  int i0 = k0 + 64 + blockIdx.y * 64;
  int j0 = k0 + 64 + blockIdx.x * 64;
#pragma unroll
  for (int it = 0; it < 4; ++it) {
    int idx = tid + it * 256;
    int r = idx >> 4, c4 = (idx & 15) * 4;
    float4 v = *(const float4*)&Mb[(size_t)(i0 + r) * NN + k0 + c4];
    As[r][c4 + 0] = f2bf(v.x * rd[c4 + 0]);
    As[r][c4 + 1] = f2bf(v.y * rd[c4 + 1]);
    As[r][c4 + 2] = f2bf(v.z * rd[c4 + 2]);
    As[r][c4 + 3] = f2bf(v.w * rd[c4 + 3]);
    float4 u = *(const float4*)&Mb[(size_t)(k0 + r) * NN + j0 + c4];
    Bt[c4 + 0][r] = f2bf(u.x);
    Bt[c4 + 1][r] = f2bf(u.y);
    Bt[c4 + 2][r] = f2bf(u.z);
    Bt[c4 + 3][r] = f2bf(u.w);
  }
  __syncthreads();
  int lane = tid & 63, w = tid >> 6;
  int rbase = w * 16;
  f32x4 acc[4] = {};
#pragma unroll
  for (int kk = 0; kk < 2; ++kk) {
    bf16x8 a = *(const bf16x8*)&As[rbase + (lane & 15)][(lane >> 4) * 8 + kk * 32];
#pragma unroll
    for (int t = 0; t < 4; ++t) {
      bf16x8 bb = *(const bf16x8*)&Bt[t * 16 + (lane & 15)][(lane >> 4) * 8 + kk * 32];
      acc[t] = __builtin_amdgcn_mfma_f32_16x16x32_bf16(a, bb, acc[t], 0, 0, 0);
    }
  }
  int rr = rbase + (lane >> 4) * 4;
  int cb = lane & 15;
#pragma unroll
  for (int t = 0; t < 4; ++t)
#pragma unroll
    for (int q = 0; q < 4; ++q)
      Mb[(size_t)(i0 + rr + q) * NN + j0 + 16 * t + cb] -= acc[t][q];
}

// ---------------- K9: exact in-LDS LU of the last 64x64 block ----------------
__global__ __launch_bounds__(256) void k9_last(float* __restrict__ M,
    float* __restrict__ slog, int* __restrict__ negc, int* __restrict__ zerc) {
  __shared__ float T[64][65];
  int b = blockIdx.x, tid = threadIdx.x;
  const float* Mb = M + (size_t)b * NN * NN;
  for (int idx = tid; idx < 4096; idx += 256)
    T[idx >> 6][idx & 63] = Mb[(size_t)(960 + (idx >> 6)) * NN + 960 + (idx & 63)];
  __syncthreads();
  for (int j = 0; j < 63; ++j) {
    float inv = 1.0f / T[j][j];
#pragma unroll
    for (int it = 0; it < 16; ++it) {
      int idx = tid + it * 256;
      int r = idx >> 6, c = idx & 63;
      if (r > j && c > j) T[r][c] -= T[r][j] * inv * T[j][c];
    }
    __syncthreads();
  }
  float lf = 0.f; int flg = 0;
  if (tid < 64) {
    float d = T[tid][tid];
    lf = logf(fabsf(d));
    flg = (d < 0.f ? 1 : 0) + (d == 0.f ? (1 << 16) : 0);
#pragma unroll
    for (int off = 32; off; off >>= 1) { lf += __shfl_down(lf, off); flg += __shfl_down(flg, off); }
    if (tid == 0) { atomicAdd(&slog[b], lf); atomicAdd(&negc[b], flg & 0xffff); atomicAdd(&zerc[b], flg >> 16); }
  }
}

// ---------------- K7: final loss ----------------
__global__ void k7_final(const float* __restrict__ rs, const int* __restrict__ roots,
    const float* __restrict__ gold_e, const float* __restrict__ slog,
    const int* __restrict__ negc, const int* __restrict__ zerc, float* __restrict__ out) {
  if (threadIdx.x == 0 && blockIdx.x == 0) {
    float s = 0.f;
    for (int b = 0; b < BB; ++b) {
      int root = roots[b];
      float gold = rs[b * NN + root] + gold_e[b];
      float ld = slog[b];
      bool pos = ((negc[b] & 1) == 0) && (zerc[b] == 0);
      float loss = 0.f;
      if (pos && !isnan(ld) && !isnan(gold)) {
        if (gold <= ld) loss = ld - gold;
      }
      if (isnan(loss) || isinf(loss)) loss = 0.f;
      s += loss;
    }
    out[0] = ALPHAC * s / (float)BB;
  }
}

extern "C" void kernel_launch(void* const* d_in, const int* in_sizes, int n_in,
                              void* d_out, int out_size, void* d_ws, size_t ws_size,
                              hipStream_t stream) {
  (void)in_sizes; (void)n_in; (void)out_size; (void)ws_size;
  const float* h_cat  = (const float*)d_in[0];
  const float* left   = (const float*)d_in[1];
  const float* right  = (const float*)d_in[2];
  const int*   roots  = (const int*)d_in[3];
  const float* W_bilin = (const float*)d_in[4];
  const float* b_bilin = (const float*)d_in[5];
  const float* W_head = (const float*)d_in[6];
  const float* W_dep  = (const float*)d_in[7];
  const float* W_r1   = (const float*)d_in[8];
  const float* b_r1   = (const float*)d_in[9];
  const float* W_r2   = (const float*)d_in[10];
  const float* b_r2   = (const float*)d_in[11];

  float* ws = (float*)d_ws;
  unsigned short* tmp_bf = (unsigned short*)(ws + OFF_TMPBF);
  unsigned short* h_bf   = (unsigned short*)(ws + OFF_HBF);
  unsigned short* BT     = (unsigned short*)(ws + OFF_BT);
  float* M     = ws + OFF_M;
  float* r1pre = M;  // alias: consumed by k1b before k2 overwrites M
  float* sm    = ws + OFF_SM;
  float* head0 = sm + O_H0;
  float* head1 = sm + O_H1;
  float* dep0  = sm + O_D0;
  float* dep1  = sm + O_D1;
  float* rs    = sm + O_RS;
  float* gold  = sm + O_GOLD;
  float* slog  = sm + O_SLOG;
  int*   negc  = (int*)(sm + O_NEG);
  int*   zerc  = (int*)(sm + O_ZER);
  float* colsum = sm + O_CS;

  // zero gold/slog/negc/zerc (32 floats) + colsum (8192 floats), contiguous
  hipMemsetAsync(gold, 0, (32 + BB * NN) * sizeof(float), stream);

  k0_cast<<<2816, 256, 0, stream>>>(h_cat, W_bilin, W_r1, h_bf, BT);
  k1_mfma<<<dim3(12, 128), 256, 0, stream>>>(h_bf, BT, tmp_bf, r1pre);
  k1b_rowscal<<<2048, 256, 0, stream>>>(h_cat, W_head, W_dep, b_r1, W_r2, b_r2, r1pre,
                                        head0, head1, dep0, dep1, rs);
  k2_mfma<<<dim3(16, 16, 8), 256, 0, stream>>>(tmp_bf, h_bf, left, right, b_bilin,
                                               head0, head1, dep0, dep1, M, gold, colsum);
  k3b_diag<<<8, 1024, 0, stream>>>(M, colsum, rs);
  for (int s = 0; s < 15; ++s)
    k6_schur<<<dim3(15 - s, 15 - s, 8), 256, 0, stream>>>(M, s * 64, slog, negc, zerc);
  k9_last<<<8, 256, 0, stream>>>(M, slog, negc, zerc);
  k7_final<<<1, 64, 0, stream>>>(rs, roots, gold, slog, negc, zerc, (float*)d_out);
}